// Round 2
// baseline (523.109 us; speedup 1.0000x reference)
//
#include <hip/hip_runtime.h>
#include <hip/hip_bf16.h>
#include <stdint.h>

typedef float v16f __attribute__((ext_vector_type(16)));
typedef short v8s  __attribute__((ext_vector_type(8)));

#define GEMM_M 8192
#define GEMM_N 4096
#define GEMM_K 4096
#define BM 256
#define BN 256
#define BK 64
#define NT (GEMM_K / BK)   // 64 K-tiles

// ---------------- prep ----------------

__device__ __forceinline__ uint16_t f2bf(float f) {
    union { float f; uint32_t u; } v; v.f = f;
    uint32_t r = v.u + 0x7FFFu + ((v.u >> 16) & 1u);   // round-to-nearest-even
    return (uint16_t)(r >> 16);
}

__device__ __forceinline__ float bf2f(uint16_t h) {
    union { uint32_t u; float f; } v; v.u = ((uint32_t)h) << 16;
    return v.f;
}

__device__ __forceinline__ void cvt8(const float* __restrict__ s, uint16_t* __restrict__ d) {
    float4 a = ((const float4*)s)[0];
    float4 b = ((const float4*)s)[1];
    union { v8s v; uint16_t u[8]; } o;
    o.u[0] = f2bf(a.x); o.u[1] = f2bf(a.y); o.u[2] = f2bf(a.z); o.u[3] = f2bf(a.w);
    o.u[4] = f2bf(b.x); o.u[5] = f2bf(b.y); o.u[6] = f2bf(b.z); o.u[7] = f2bf(b.w);
    *(v8s*)d = o.v;
}

__global__ void prep_cvt_kernel(const float* __restrict__ X, const float* __restrict__ W,
                                uint16_t* __restrict__ Xb, uint16_t* __restrict__ Wb,
                                size_t x8) {
    size_t i = (size_t)blockIdx.x * blockDim.x + threadIdx.x;
    if (i < x8) {
        cvt8(X + i * 8, Xb + i * 8);
    } else {
        size_t j = i - x8;
        cvt8(W + j * 8, Wb + j * 8);
    }
}

__global__ void scatter_bf16_kernel(uint16_t* __restrict__ Wb, const float* __restrict__ vals,
                                    const int* __restrict__ rows, const int* __restrict__ cols,
                                    int nnz) {
    int i = blockIdx.x * blockDim.x + threadIdx.x;
    if (i >= nnz) return;
    size_t idx = (size_t)rows[i] * GEMM_K + cols[i];
    uint32_t* addr = (uint32_t*)Wb + (idx >> 1);
    const bool hi = idx & 1;
    const float v = vals[i];   // * SCALING=1.0
    uint32_t cur = *addr, assumed;
    do {
        assumed = cur;
        uint16_t h = hi ? (uint16_t)(assumed >> 16) : (uint16_t)(assumed & 0xFFFFu);
        uint16_t nh = f2bf(bf2f(h) + v);
        uint32_t nw = hi ? ((assumed & 0x0000FFFFu) | ((uint32_t)nh << 16))
                         : ((assumed & 0xFFFF0000u) | (uint32_t)nh);
        if (nw == assumed) break;
        cur = atomicCAS(addr, assumed, nw);
    } while (cur != assumed);
}

// ---------------- GEMM: 256x256 tile, 8-wave, 4-phase/tile, 32x32x16 MFMA ----------------
// C[M,N] = A[M,K] bf16 * B[N,K]^T bf16 + bias[N], fp32 out.
//
// Changes vs R1 (both attack the ~50% idle window):
//  1. MFMA shape 16x16x32 -> 32x32x16: same FLOPs in ~17% less pipe time (2495 vs 2075 TF
//     ceiling), half the MFMA instruction count. LDS read traffic unchanged (geometry-fixed).
//     A/B operand layout: lane holds [row=lane&31][k=(lane>>5)*8+j]; C/D: col=lane&31,
//     row=(r&3)+8*(r>>2)+4*(lane>>5)  [m74/m101 verified].
//  2. ONE barrier per phase instead of two. Correctness: every STAGE targets a slot whose
//     last ds_reads completed (per-wave lgkmcnt(0) before that phase's MFMA) before the
//     previous phase's post-MFMA barrier. P3 keeps its pre-MFMA VM6+BAR (cross-wave
//     visibility of next tile's staged data); its post-MFMA barrier is dropped (MFMA is
//     reg-only, next phase's read targets already visible). 8 -> 4 rendezvous per tile,
//     and waves de-phase within a phase: one wave drains lgkmcnt while its SIMD partner
//     runs MFMA (the role-split that makes setprio pay).
//  Counted-vmcnt FIFO unchanged: per-wave stage order is program order, so vmcnt(6) at P3
//  still completes exactly tile t+1's four half-tiles.

__device__ __forceinline__ void gload_lds16(const void* g, void* lds) {
    __builtin_amdgcn_global_load_lds(
        (const __attribute__((address_space(1))) void*)(uintptr_t)g,
        (__attribute__((address_space(3))) void*)(uintptr_t)lds,
        16, 0, 0);
}

__global__ __launch_bounds__(512, 2) void gemm_bt_kernel(
    const uint16_t* __restrict__ A,   // [M,K] bf16 bits
    const uint16_t* __restrict__ B,   // [N,K] bf16 bits
    const float* __restrict__ bias,   // [N]
    float* __restrict__ C)            // [M,N] fp32
{
    __shared__ __attribute__((aligned(16))) uint16_t As[2][2][128 * BK];  // 64 KiB
    __shared__ __attribute__((aligned(16))) uint16_t Bs[2][2][128 * BK];  // 64 KiB

    const int tid  = threadIdx.x;
    const int lane = tid & 63;
    const int wid  = tid >> 6;     // 0..7
    const int wm2  = wid >> 1;     // 0..3: 32-row A band within the 128-row half
    const int wn2  = wid & 1;      // 0..1: 64-col B band within the 128-col half
    const int l32  = lane & 31;
    const int g    = lane >> 5;    // k-group within a 16-k MFMA slice

    // T1: bijective XCD swizzle (512 % 8 == 0). Each XCD owns 4 consecutive m-panels.
    const int bid = blockIdx.x;               // 0..511
    const int swz = (bid & 7) * 64 + (bid >> 3);
    const int m0  = (swz >> 4) * BM;          // 32 m-tiles
    const int n0  = (swz & 15) * BN;          // 16 n-tiles

    // staging: transfer (wid, lane) covers half-row wid*16 + (lane>>3); lane fetches
    // pre-swizzled global k-chunk ((lane&7)^(lane>>3)); LDS dest linear.
    // LDS slot s of half-local row r holds global chunk s ^ (r&7).
    const int srow = wid * 16 + (lane >> 3);
    const int skc  = ((lane & 7) ^ (lane >> 3)) * 8;
    const uint16_t* gA = A + (size_t)(m0 + srow) * GEMM_K + skc;
    const uint16_t* gB = B + (size_t)(n0 + srow) * GEMM_K + skc;
    const int ldso = wid * 1024 + lane * 8;   // elem offset within one 8192-elem half

#define STAGE(gbase, hrow, s, ldshalf)  do {                                   \
        const uint16_t* _g = (gbase) + (size_t)(hrow) * GEMM_K + (s) * BK;     \
        uint16_t* _l = (ldshalf) + ldso;                                       \
        gload_lds16(_g, _l);                                                   \
        gload_lds16(_g + (size_t)8 * GEMM_K, _l + 512);                        \
    } while (0)

    v16f acc00[2], acc10[2], acc01[2], acc11[2];
#pragma unroll
    for (int nj = 0; nj < 2; ++nj) {
        acc00[nj] = (v16f)(0.f);
        acc10[nj] = (v16f)(0.f);
        acc01[nj] = (v16f)(0.f);
        acc11[nj] = (v16f)(0.f);
    }

    v8s a0F[4], a1F[4], bF[2][4];   // all statically indexed (rule #20)

    // fragment read: half-local row rh holds logical chunk c at elem rh*64 + ((c^(rh&7))*8)
#define LDA32(dst, hp) do {                                                    \
        const int _rh = wm2 * 32 + l32;                                        \
        const uint16_t* _p = (hp) + _rh * BK;                                  \
        const int _x = _rh & 7;                                                \
        _Pragma("unroll")                                                      \
        for (int ks = 0; ks < 4; ++ks) {                                       \
            const int _c = ks * 2 + g;                                         \
            dst[ks] = *(const v8s*)(_p + ((_c ^ _x) << 3));                    \
        } } while (0)

#define LDB32(hp) do {                                                         \
        _Pragma("unroll")                                                      \
        for (int nj = 0; nj < 2; ++nj) {                                       \
            const int _rh = wn2 * 64 + nj * 32 + l32;                          \
            const uint16_t* _p = (hp) + _rh * BK;                              \
            const int _x = _rh & 7;                                            \
            _Pragma("unroll")                                                  \
            for (int ks = 0; ks < 4; ++ks) {                                   \
                const int _c = ks * 2 + g;                                     \
                bF[nj][ks] = *(const v8s*)(_p + ((_c ^ _x) << 3));             \
            } } } while (0)

#define MM32(accq, aT) do {                                                    \
        _Pragma("unroll")                                                      \
        for (int ks = 0; ks < 4; ++ks)                                         \
        _Pragma("unroll")                                                      \
        for (int nj = 0; nj < 2; ++nj)                                         \
            accq[nj] = __builtin_amdgcn_mfma_f32_32x32x16_bf16(                \
                aT[ks], bF[nj][ks], accq[nj], 0, 0, 0);                        \
    } while (0)

#define BAR()   __builtin_amdgcn_s_barrier()
#define LGKM0() asm volatile("s_waitcnt lgkmcnt(0)" ::: "memory")
#define VM6()   asm volatile("s_waitcnt vmcnt(6)" ::: "memory")
#define SCHED() __builtin_amdgcn_sched_barrier(0)
#define PRIO(p) __builtin_amdgcn_s_setprio(p)

    // ---- prologue: tile0 fully + 3 halves of tile1; vmcnt(6) leaves those 3 in flight ----
    STAGE(gA, 0,   0, &As[0][0][0]);
    STAGE(gA, 128, 0, &As[0][1][0]);
    STAGE(gB, 0,   0, &Bs[0][0][0]);
    STAGE(gB, 128, 0, &Bs[0][1][0]);
    STAGE(gA, 0,   1, &As[1][0][0]);
    STAGE(gA, 128, 1, &As[1][1][0]);
    STAGE(gB, 0,   1, &Bs[1][0][0]);
    SCHED(); VM6();
    BAR(); SCHED();

#define TILE(t, b) do {                                                        \
        const int s1 = ((t) + 1) & (NT - 1);                                   \
        const int s2 = ((t) + 2) & (NT - 1);                                   \
        /* P0: quadrant (0,0) — 12 ds_reads */                                 \
        LDA32(a0F, &As[b][0][0]);                                              \
        LDB32(&Bs[b][0][0]);                                                   \
        STAGE(gB, 128, s1, &Bs[(b) ^ 1][1][0]);                                \
        LGKM0(); SCHED();                                                      \
        PRIO(1); MM32(acc00, a0F); PRIO(0);                                    \
        SCHED(); BAR(); SCHED();                                               \
        /* P1: quadrant (1,0) — 4 ds_reads */                                  \
        LDA32(a1F, &As[b][1][0]);                                              \
        STAGE(gA, 0, s2, &As[b][0][0]);                                        \
        LGKM0(); SCHED();                                                      \
        PRIO(1); MM32(acc10, a1F); PRIO(0);                                    \
        SCHED(); BAR(); SCHED();                                               \
        /* P2: quadrant (0,1) — 8 ds_reads */                                  \
        LDB32(&Bs[b][1][0]);                                                   \
        STAGE(gA, 128, s2, &As[b][1][0]);                                      \
        LGKM0(); SCHED();                                                      \
        PRIO(1); MM32(acc01, a0F); PRIO(0);                                    \
        SCHED(); BAR(); SCHED();                                               \
        /* P3: quadrant (1,1) — the one counted vmcnt; MFMA overlaps next P0 reads */ \
        STAGE(gB, 0, s2, &Bs[b][0][0]);                                        \
        SCHED(); VM6();                                                        \
        BAR(); SCHED();                                                        \
        PRIO(1); MM32(acc11, a1F); PRIO(0);                                    \
        SCHED();                                                               \
    } while (0)

    for (int t = 0; t < NT; t += 2) {
        TILE(t, 0);
        TILE(t + 1, 1);
    }

    // epilogue: 32x32 C/D layout — col = lane&31, row = (r&3) + 8*(r>>2) + 4*(lane>>5)
#define WR32(accq, QM, QN) do {                                                \
        _Pragma("unroll")                                                      \
        for (int nj = 0; nj < 2; ++nj) {                                       \
            const int col = n0 + (QN) * 128 + wn2 * 64 + nj * 32 + l32;        \
            const float bj = bias[col];                                        \
            const int rbase = m0 + (QM) * 128 + wm2 * 32 + 4 * g;              \
            _Pragma("unroll")                                                  \
            for (int r = 0; r < 16; ++r) {                                     \
                const int row = rbase + (r & 3) + 8 * (r >> 2);                \
                C[(size_t)row * GEMM_N + col] = accq[nj][r] + bj;              \
            }                                                                  \
        } } while (0)

    WR32(acc00, 0, 0);
    WR32(acc10, 1, 0);
    WR32(acc01, 0, 1);
    WR32(acc11, 1, 1);

#undef STAGE
#undef LDA32
#undef LDB32
#undef MM32
#undef BAR
#undef LGKM0
#undef VM6
#undef SCHED
#undef PRIO
#undef TILE
#undef WR32
}

// ---------------- launch ----------------

extern "C" void kernel_launch(void* const* d_in, const int* in_sizes, int n_in,
                              void* d_out, int out_size, void* d_ws, size_t ws_size,
                              hipStream_t stream) {
    const float* x      = (const float*)d_in[0];   // [4,2048,4096] = [8192,4096]
    const float* weight = (const float*)d_in[1];   // [4096,4096]
    const float* bias   = (const float*)d_in[2];   // [4096]
    const float* sw     = (const float*)d_in[3];   // [nnz]
    const int*   sidx   = (const int*)d_in[4];     // [2,nnz]
    const int nnz = in_sizes[3];

    const size_t welems = (size_t)GEMM_N * GEMM_K;        // 16,777,216
    const size_t xelems = (size_t)GEMM_M * GEMM_K;        // 33,554,432

    uint16_t* Wb = (uint16_t*)d_ws;
    uint16_t* Xb = (uint16_t*)((char*)d_ws + welems * sizeof(uint16_t));

    const size_t x8 = xelems / 8;
    const size_t w8 = welems / 8;
    const int prep_blocks = (int)((x8 + w8) / 256);

    prep_cvt_kernel<<<dim3(prep_blocks), 256, 0, stream>>>(x, weight, Xb, Wb, x8);
    scatter_bf16_kernel<<<dim3((nnz + 255) / 256), 256, 0, stream>>>(
        Wb, sw, sidx, sidx + nnz, nnz);
    gemm_bt_kernel<<<dim3((GEMM_M / BM) * (GEMM_N / BN)), 512, 0, stream>>>(
        Xb, Wb, bias, (float*)d_out);
}

// Round 4
// 499.200 us; speedup vs baseline: 1.0479x; 1.0479x over previous
//
#include <hip/hip_runtime.h>
#include <hip/hip_bf16.h>
#include <stdint.h>

typedef float v4f __attribute__((ext_vector_type(4)));
typedef short v8s __attribute__((ext_vector_type(8)));

#define GEMM_M 8192
#define GEMM_N 4096
#define GEMM_K 4096
#define BM 256
#define BN 256
#define BK 64
#define NT (GEMM_K / BK)   // 64 K-tiles

// ---------------- prep ----------------

__device__ __forceinline__ uint16_t f2bf(float f) {
    union { float f; uint32_t u; } v; v.f = f;
    uint32_t r = v.u + 0x7FFFu + ((v.u >> 16) & 1u);   // round-to-nearest-even
    return (uint16_t)(r >> 16);
}

__device__ __forceinline__ float bf2f(uint16_t h) {
    union { uint32_t u; float f; } v; v.u = ((uint32_t)h) << 16;
    return v.f;
}

__device__ __forceinline__ void cvt8(const float* __restrict__ s, uint16_t* __restrict__ d) {
    float4 a = ((const float4*)s)[0];
    float4 b = ((const float4*)s)[1];
    union { v8s v; uint16_t u[8]; } o;
    o.u[0] = f2bf(a.x); o.u[1] = f2bf(a.y); o.u[2] = f2bf(a.z); o.u[3] = f2bf(a.w);
    o.u[4] = f2bf(b.x); o.u[5] = f2bf(b.y); o.u[6] = f2bf(b.z); o.u[7] = f2bf(b.w);
    *(v8s*)d = o.v;
}

__global__ void prep_cvt_kernel(const float* __restrict__ X, const float* __restrict__ W,
                                uint16_t* __restrict__ Xb, uint16_t* __restrict__ Wb,
                                size_t x8) {
    size_t i = (size_t)blockIdx.x * blockDim.x + threadIdx.x;
    if (i < x8) {
        cvt8(X + i * 8, Xb + i * 8);
    } else {
        size_t j = i - x8;
        cvt8(W + j * 8, Wb + j * 8);
    }
}

__global__ void scatter_bf16_kernel(uint16_t* __restrict__ Wb, const float* __restrict__ vals,
                                    const int* __restrict__ rows, const int* __restrict__ cols,
                                    int nnz) {
    int i = blockIdx.x * blockDim.x + threadIdx.x;
    if (i >= nnz) return;
    size_t idx = (size_t)rows[i] * GEMM_K + cols[i];
    uint32_t* addr = (uint32_t*)Wb + (idx >> 1);
    const bool hi = idx & 1;
    const float v = vals[i];   // * SCALING=1.0
    uint32_t cur = *addr, assumed;
    do {
        assumed = cur;
        uint16_t h = hi ? (uint16_t)(assumed >> 16) : (uint16_t)(assumed & 0xFFFFu);
        uint16_t nh = f2bf(bf2f(h) + v);
        uint32_t nw = hi ? ((assumed & 0x0000FFFFu) | ((uint32_t)nh << 16))
                         : ((assumed & 0xFFFF0000u) | (uint32_t)nh);
        if (nw == assumed) break;
        cur = atomicCAS(addr, assumed, nw);
    } while (cur != assumed);
}

// ---------------- GEMM: 256x256 tile, 8-wave, 4-phase/tile, 16x16x32 MFMA ----------------
// C[M,N] = A[M,K] bf16 * B[N,K]^T bf16 + bias[N], fp32 out.
//
// R3 vs R1 (single change class — UNPIN the compiler, per m141's lesson):
//  - 16x16x32 shape kept (R2's 32x32 read mapping measured 25M bank conflicts; this
//    pattern measured 0).
//  - All sched_barrier(0) removed from the K-loop. The ds_reads are compiler-visible C++
//    loads, so MFMA cannot hoist past its own operands (rule #18 hazard doesn't apply);
//    the compiler now emits counted lgkmcnt(N) so the first MFMAs start while later
//    fragments are still returning, and next-phase reads may interleave under this
//    phase's MFMA cluster.
//  - The correctness lgkmcnt(0) moved AFTER each MFMA cluster (before the phase-end
//    barrier). That is all the stage-overwrite argument needs: a slot staged in phase p
//    had its last reads completed before the barrier ending phase p-1. Since all 12
//    fragments are consumed inside the cluster and DS returns are in-order, this drain
//    is free in the steady state.
//  - vmcnt(6) FIFO unchanged: cross-phase stage order is pinned by the "memory"-clobber
//    waitcnt asms; the 2 gloads within one STAGE are an adjacent pair (reorder harmless).
//    Prologue keeps one sched_barrier between tile-0 and tile-1 stage groups so the
//    oldest-8 arithmetic of the first vmcnt(6) holds.

__device__ __forceinline__ void gload_lds16(const void* g, void* lds) {
    __builtin_amdgcn_global_load_lds(
        (const __attribute__((address_space(1))) void*)(uintptr_t)g,
        (__attribute__((address_space(3))) void*)(uintptr_t)lds,
        16, 0, 0);
}

__global__ __launch_bounds__(512, 2) void gemm_bt_kernel(
    const uint16_t* __restrict__ A,   // [M,K] bf16 bits
    const uint16_t* __restrict__ B,   // [N,K] bf16 bits
    const float* __restrict__ bias,   // [N]
    float* __restrict__ C)            // [M,N] fp32
{
    __shared__ __attribute__((aligned(16))) uint16_t As[2][2][128 * BK];  // 64 KiB
    __shared__ __attribute__((aligned(16))) uint16_t Bs[2][2][128 * BK];  // 64 KiB

    const int tid  = threadIdx.x;
    const int lane = tid & 63;
    const int wid  = tid >> 6;     // 0..7
    const int wm2  = wid >> 1;     // 0..3: 32-row A band within the 128-row half
    const int wn2  = wid & 1;      // 0..1: 64-col B band within the 128-col half
    const int lrow = lane & 15;
    const int quad = lane >> 4;
    const int xr   = lane & 7;     // == lrow & 7

    // T1: bijective XCD swizzle (512 % 8 == 0). Each XCD owns 4 consecutive m-panels.
    const int bid = blockIdx.x;               // 0..511
    const int swz = (bid & 7) * 64 + (bid >> 3);
    const int m0  = (swz >> 4) * BM;          // 32 m-tiles
    const int n0  = (swz & 15) * BN;          // 16 n-tiles

    // staging: transfer (wid, lane) covers half-row wid*16 + (lane>>3); lane fetches
    // pre-swizzled global k-chunk ((lane&7)^(lane>>3)); LDS dest linear.
    // LDS slot s of half-local row r holds global chunk s ^ (r&7).
    const int srow = wid * 16 + (lane >> 3);
    const int skc  = ((lane & 7) ^ (lane >> 3)) * 8;
    const uint16_t* gA = A + (size_t)(m0 + srow) * GEMM_K + skc;
    const uint16_t* gB = B + (size_t)(n0 + srow) * GEMM_K + skc;
    const int ldso = wid * 1024 + lane * 8;   // elem offset within one 8192-elem half

#define STAGE(gbase, hrow, s, ldshalf)  do {                                   \
        const uint16_t* _g = (gbase) + (size_t)(hrow) * GEMM_K + (s) * BK;     \
        uint16_t* _l = (ldshalf) + ldso;                                       \
        gload_lds16(_g, _l);                                                   \
        gload_lds16(_g + (size_t)8 * GEMM_K, _l + 512);                        \
    } while (0)

    v4f acc00[2][4], acc10[2][4], acc01[2][4], acc11[2][4];
#pragma unroll
    for (int mi = 0; mi < 2; ++mi)
#pragma unroll
        for (int nj = 0; nj < 4; ++nj) {
            acc00[mi][nj] = (v4f){0.f, 0.f, 0.f, 0.f};
            acc10[mi][nj] = (v4f){0.f, 0.f, 0.f, 0.f};
            acc01[mi][nj] = (v4f){0.f, 0.f, 0.f, 0.f};
            acc11[mi][nj] = (v4f){0.f, 0.f, 0.f, 0.f};
        }

    v8s a0F[2][2], a1F[2][2], bF[4][2];   // all statically indexed (rule #20)

    // fragment read: half-local row rh holds logical chunk c at elem rh*64 + ((c^(rh&7))*8)
#define LDA(dst, hp) do {                                                      \
        _Pragma("unroll")                                                      \
        for (int mi = 0; mi < 2; ++mi)                                         \
        _Pragma("unroll")                                                      \
        for (int ks = 0; ks < 2; ++ks) {                                       \
            const int rh = wm2 * 32 + mi * 16 + lrow;                          \
            const int c  = ks * 4 + quad;                                      \
            dst[mi][ks] = *(const v8s*)((hp) + rh * BK + ((c ^ xr) << 3));     \
        } } while (0)

#define LDB(hp) do {                                                           \
        _Pragma("unroll")                                                      \
        for (int nj = 0; nj < 4; ++nj)                                         \
        _Pragma("unroll")                                                      \
        for (int ks = 0; ks < 2; ++ks) {                                       \
            const int rh = wn2 * 64 + nj * 16 + lrow;                          \
            const int c  = ks * 4 + quad;                                      \
            bF[nj][ks] = *(const v8s*)((hp) + rh * BK + ((c ^ xr) << 3));      \
        } } while (0)

#define MM(accq, aT) do {                                                      \
        _Pragma("unroll")                                                      \
        for (int ks = 0; ks < 2; ++ks)                                         \
        _Pragma("unroll")                                                      \
        for (int mi = 0; mi < 2; ++mi)                                         \
        _Pragma("unroll")                                                      \
        for (int nj = 0; nj < 4; ++nj)                                         \
            accq[mi][nj] = __builtin_amdgcn_mfma_f32_16x16x32_bf16(            \
                aT[mi][ks], bF[nj][ks], accq[mi][nj], 0, 0, 0);                \
    } while (0)

#define BAR()   __builtin_amdgcn_s_barrier()
#define LGKM0() asm volatile("s_waitcnt lgkmcnt(0)" ::: "memory")
#define VM6()   asm volatile("s_waitcnt vmcnt(6)" ::: "memory")
#define SCHED() __builtin_amdgcn_sched_barrier(0)
#define PRIO(p) __builtin_amdgcn_s_setprio(p)

    // ---- prologue: tile0 fully + 3 halves of tile1; vmcnt(6) leaves those 3 in flight ----
    STAGE(gA, 0,   0, &As[0][0][0]);
    STAGE(gA, 128, 0, &As[0][1][0]);
    STAGE(gB, 0,   0, &Bs[0][0][0]);
    STAGE(gB, 128, 0, &Bs[0][1][0]);
    SCHED();                       // keep tile-0 loads as the oldest 8 in the vmcnt FIFO
    STAGE(gA, 0,   1, &As[1][0][0]);
    STAGE(gA, 128, 1, &As[1][1][0]);
    STAGE(gB, 0,   1, &Bs[1][0][0]);
    VM6();
    BAR();

#define TILE(t, b) do {                                                        \
        const int s1 = ((t) + 1) & (NT - 1);                                   \
        const int s2 = ((t) + 2) & (NT - 1);                                   \
        /* P0: quadrant (0,0) — 12 ds_reads */                                 \
        LDA(a0F, &As[b][0][0]);                                                \
        LDB(&Bs[b][0][0]);                                                     \
        STAGE(gB, 128, s1, &Bs[(b) ^ 1][1][0]);                                \
        BAR();                                                                 \
        PRIO(1); MM(acc00, a0F); PRIO(0);                                      \
        LGKM0();                                                               \
        BAR();                                                                 \
        /* P1: quadrant (1,0) — 4 ds_reads */                                  \
        LDA(a1F, &As[b][1][0]);                                                \
        STAGE(gA, 0, s2, &As[b][0][0]);                                        \
        BAR();                                                                 \
        PRIO(1); MM(acc10, a1F); PRIO(0);                                      \
        LGKM0();                                                               \
        BAR();                                                                 \
        /* P2: quadrant (0,1) — 8 ds_reads */                                  \
        LDB(&Bs[b][1][0]);                                                     \
        STAGE(gA, 128, s2, &As[b][1][0]);                                      \
        BAR();                                                                 \
        PRIO(1); MM(acc01, a0F); PRIO(0);                                      \
        LGKM0();                                                               \
        BAR();                                                                 \
        /* P3: quadrant (1,1) — the one counted vmcnt of this K-tile */        \
        STAGE(gB, 0, s2, &Bs[b][0][0]);                                        \
        VM6();                                                                 \
        BAR();                                                                 \
        PRIO(1); MM(acc11, a1F); PRIO(0);                                      \
    } while (0)

    for (int t = 0; t < NT; t += 2) {
        TILE(t, 0);
        TILE(t + 1, 1);
    }

    // epilogue: C/D layout col = lane&15, row = quad*4 + reg  [m89/m91 verified]
#define WR(accq, QM, QN) do {                                                  \
        _Pragma("unroll")                                                      \
        for (int nj = 0; nj < 4; ++nj) {                                       \
            const int col = n0 + (QN) * 128 + wn2 * 64 + nj * 16 + lrow;       \
            const float bj = bias[col];                                        \
            _Pragma("unroll")                                                  \
            for (int mi = 0; mi < 2; ++mi) {                                   \
                const int row = m0 + (QM) * 128 + wm2 * 32 + mi * 16 + quad * 4; \
                float* cp = C + (size_t)row * GEMM_N + col;                    \
                _Pragma("unroll")                                              \
                for (int r = 0; r < 4; ++r)                                    \
                    cp[(size_t)r * GEMM_N] = accq[mi][nj][r] + bj;             \
            }                                                                  \
        } } while (0)

    WR(acc00, 0, 0);
    WR(acc10, 1, 0);
    WR(acc01, 0, 1);
    WR(acc11, 1, 1);

#undef STAGE
#undef LDA
#undef LDB
#undef MM
#undef BAR
#undef LGKM0
#undef VM6
#undef SCHED
#undef PRIO
#undef TILE
#undef WR
}

// ---------------- launch ----------------

extern "C" void kernel_launch(void* const* d_in, const int* in_sizes, int n_in,
                              void* d_out, int out_size, void* d_ws, size_t ws_size,
                              hipStream_t stream) {
    const float* x      = (const float*)d_in[0];   // [4,2048,4096] = [8192,4096]
    const float* weight = (const float*)d_in[1];   // [4096,4096]
    const float* bias   = (const float*)d_in[2];   // [4096]
    const float* sw     = (const float*)d_in[3];   // [nnz]
    const int*   sidx   = (const int*)d_in[4];     // [2,nnz]
    const int nnz = in_sizes[3];

    const size_t welems = (size_t)GEMM_N * GEMM_K;        // 16,777,216
    const size_t xelems = (size_t)GEMM_M * GEMM_K;        // 33,554,432

    uint16_t* Wb = (uint16_t*)d_ws;
    uint16_t* Xb = (uint16_t*)((char*)d_ws + welems * sizeof(uint16_t));

    const size_t x8 = xelems / 8;
    const size_t w8 = welems / 8;
    const int prep_blocks = (int)((x8 + w8) / 256);

    prep_cvt_kernel<<<dim3(prep_blocks), 256, 0, stream>>>(x, weight, Xb, Wb, x8);
    scatter_bf16_kernel<<<dim3((nnz + 255) / 256), 256, 0, stream>>>(
        Wb, sw, sidx, sidx + nnz, nnz);
    gemm_bt_kernel<<<dim3((GEMM_M / BM) * (GEMM_N / BN)), 512, 0, stream>>>(
        Xb, Wb, bias, (float*)d_out);
}

// Round 5
// 496.162 us; speedup vs baseline: 1.0543x; 1.0061x over previous
//
#include <hip/hip_runtime.h>
#include <hip/hip_bf16.h>
#include <stdint.h>

typedef float v4f __attribute__((ext_vector_type(4)));
typedef short v8s __attribute__((ext_vector_type(8)));

#define GEMM_M 8192
#define GEMM_N 4096
#define GEMM_K 4096
#define BM 256
#define BN 256
#define BK 64
#define NT (GEMM_K / BK)   // 64 K-tiles

// ---------------- prep ----------------

__device__ __forceinline__ uint16_t f2bf(float f) {
    union { float f; uint32_t u; } v; v.f = f;
    uint32_t r = v.u + 0x7FFFu + ((v.u >> 16) & 1u);   // round-to-nearest-even
    return (uint16_t)(r >> 16);
}

__device__ __forceinline__ float bf2f(uint16_t h) {
    union { uint32_t u; float f; } v; v.u = ((uint32_t)h) << 16;
    return v.f;
}

__device__ __forceinline__ void cvt8(const float* __restrict__ s, uint16_t* __restrict__ d) {
    float4 a = ((const float4*)s)[0];
    float4 b = ((const float4*)s)[1];
    union { v8s v; uint16_t u[8]; } o;
    o.u[0] = f2bf(a.x); o.u[1] = f2bf(a.y); o.u[2] = f2bf(a.z); o.u[3] = f2bf(a.w);
    o.u[4] = f2bf(b.x); o.u[5] = f2bf(b.y); o.u[6] = f2bf(b.z); o.u[7] = f2bf(b.w);
    *(v8s*)d = o.v;
}

__global__ void prep_cvt_kernel(const float* __restrict__ X, const float* __restrict__ W,
                                uint16_t* __restrict__ Xb, uint16_t* __restrict__ Wb,
                                size_t x8) {
    size_t i = (size_t)blockIdx.x * blockDim.x + threadIdx.x;
    if (i < x8) {
        cvt8(X + i * 8, Xb + i * 8);
    } else {
        size_t j = i - x8;
        cvt8(W + j * 8, Wb + j * 8);
    }
}

__global__ void scatter_bf16_kernel(uint16_t* __restrict__ Wb, const float* __restrict__ vals,
                                    const int* __restrict__ rows, const int* __restrict__ cols,
                                    int nnz) {
    int i = blockIdx.x * blockDim.x + threadIdx.x;
    if (i >= nnz) return;
    size_t idx = (size_t)rows[i] * GEMM_K + cols[i];
    uint32_t* addr = (uint32_t*)Wb + (idx >> 1);
    const bool hi = idx & 1;
    const float v = vals[i];   // * SCALING=1.0
    uint32_t cur = *addr, assumed;
    do {
        assumed = cur;
        uint16_t h = hi ? (uint16_t)(assumed >> 16) : (uint16_t)(assumed & 0xFFFFu);
        uint16_t nh = f2bf(bf2f(h) + v);
        uint32_t nw = hi ? ((assumed & 0x0000FFFFu) | ((uint32_t)nh << 16))
                         : ((assumed & 0xFFFF0000u) | (uint32_t)nh);
        if (nw == assumed) break;
        cur = atomicCAS(addr, assumed, nw);
    } while (cur != assumed);
}

// ---------------- GEMM: 256x256 tile, 8-wave, 4-phase/tile, reg-double-buffered frags ----
// C[M,N] = A[M,K] bf16 * B[N,K]^T bf16 + bias[N], fp32 out.
//
// R5 vs R4 (single change class — one-phase REGISTER read-ahead):
//  - Every phase's MFMA consumes fragments ds_read one phase EARLIER (second register
//    set bF0/bF1; a0F/a1F already alternate). MM(p) has no LDS dependency at issue.
//    Read phases: P0:4 (A1), P1:8 (B1), P2:0, P3:12 (NEXT tile's A0+B0, after VM6+BAR).
//  - One barrier per phase: { reads(p+1); BAR; STAGE(slot_p); MM(p) }. STAGE is after
//    the BAR, so slot-overwrite safety is rigorous with NO explicit lgkmcnt(0):
//    slot staged at p was consumed inside MM(p-1) (compiler operand waits), and BAR(p)
//    proves every wave finished MM(p-1). Per-slot audit:
//      P0 stages B1(t+1)->b^1 : B1(b^1) consumed MM(t-1,P2/P3), 2+ barriers ago.
//      P1 stages A0(t+2)->b   : A0(b) reads (issued t-1P3) consumed MM(t,P0); BAR(P1).
//      P2 stages A1(t+2)->b   : A1(b) reads (tP0) consumed MM(t,P1); BAR(P2).
//      P3 stages B0(t+2)->b   : B0(b) reads (t-1P3) consumed MM(t,P1); BAR(P2)+program order.
//  - vmcnt(6) FIFO identical to R4 (same per-wave stage issue order): at each P3 the 8
//    oldest outstanding loads are exactly tile t+1's four halves; VM6 then BAR makes
//    them visible before the P3 cross-tile prefetch reads.
//  - Prologue: stage t0 (4 halves) then t1 (3 halves), VM6, BAR, preload a0F/bF0.

__device__ __forceinline__ void gload_lds16(const void* g, void* lds) {
    __builtin_amdgcn_global_load_lds(
        (const __attribute__((address_space(1))) void*)(uintptr_t)g,
        (__attribute__((address_space(3))) void*)(uintptr_t)lds,
        16, 0, 0);
}

__global__ __launch_bounds__(512, 2) void gemm_bt_kernel(
    const uint16_t* __restrict__ A,   // [M,K] bf16 bits
    const uint16_t* __restrict__ B,   // [N,K] bf16 bits
    const float* __restrict__ bias,   // [N]
    float* __restrict__ C)            // [M,N] fp32
{
    __shared__ __attribute__((aligned(16))) uint16_t As[2][2][128 * BK];  // 64 KiB
    __shared__ __attribute__((aligned(16))) uint16_t Bs[2][2][128 * BK];  // 64 KiB

    const int tid  = threadIdx.x;
    const int lane = tid & 63;
    const int wid  = tid >> 6;     // 0..7
    const int wm2  = wid >> 1;     // 0..3: 32-row A band within the 128-row half
    const int wn2  = wid & 1;      // 0..1: 64-col B band within the 128-col half
    const int lrow = lane & 15;
    const int quad = lane >> 4;
    const int xr   = lane & 7;     // == lrow & 7

    // T1: bijective XCD swizzle (512 % 8 == 0). Each XCD owns 4 consecutive m-panels.
    const int bid = blockIdx.x;               // 0..511
    const int swz = (bid & 7) * 64 + (bid >> 3);
    const int m0  = (swz >> 4) * BM;          // 32 m-tiles
    const int n0  = (swz & 15) * BN;          // 16 n-tiles

    // staging: transfer (wid, lane) covers half-row wid*16 + (lane>>3); lane fetches
    // pre-swizzled global k-chunk ((lane&7)^(lane>>3)); LDS dest linear.
    // LDS slot s of half-local row r holds global chunk s ^ (r&7).
    const int srow = wid * 16 + (lane >> 3);
    const int skc  = ((lane & 7) ^ (lane >> 3)) * 8;
    const uint16_t* gA = A + (size_t)(m0 + srow) * GEMM_K + skc;
    const uint16_t* gB = B + (size_t)(n0 + srow) * GEMM_K + skc;
    const int ldso = wid * 1024 + lane * 8;   // elem offset within one 8192-elem half

#define STAGE(gbase, hrow, s, ldshalf)  do {                                   \
        const uint16_t* _g = (gbase) + (size_t)(hrow) * GEMM_K + (s) * BK;     \
        uint16_t* _l = (ldshalf) + ldso;                                       \
        gload_lds16(_g, _l);                                                   \
        gload_lds16(_g + (size_t)8 * GEMM_K, _l + 512);                        \
    } while (0)

    v4f acc00[2][4], acc10[2][4], acc01[2][4], acc11[2][4];
#pragma unroll
    for (int mi = 0; mi < 2; ++mi)
#pragma unroll
        for (int nj = 0; nj < 4; ++nj) {
            acc00[mi][nj] = (v4f){0.f, 0.f, 0.f, 0.f};
            acc10[mi][nj] = (v4f){0.f, 0.f, 0.f, 0.f};
            acc01[mi][nj] = (v4f){0.f, 0.f, 0.f, 0.f};
            acc11[mi][nj] = (v4f){0.f, 0.f, 0.f, 0.f};
        }

    v8s a0F[2][2], a1F[2][2], bF0[4][2], bF1[4][2];   // all statically indexed (rule #20)

    // fragment read: half-local row rh holds logical chunk c at elem rh*64 + ((c^(rh&7))*8)
#define LDA(dst, hp) do {                                                      \
        _Pragma("unroll")                                                      \
        for (int mi = 0; mi < 2; ++mi)                                         \
        _Pragma("unroll")                                                      \
        for (int ks = 0; ks < 2; ++ks) {                                       \
            const int rh = wm2 * 32 + mi * 16 + lrow;                          \
            const int c  = ks * 4 + quad;                                      \
            dst[mi][ks] = *(const v8s*)((hp) + rh * BK + ((c ^ xr) << 3));     \
        } } while (0)

#define LDB(dst, hp) do {                                                      \
        _Pragma("unroll")                                                      \
        for (int nj = 0; nj < 4; ++nj)                                         \
        _Pragma("unroll")                                                      \
        for (int ks = 0; ks < 2; ++ks) {                                       \
            const int rh = wn2 * 64 + nj * 16 + lrow;                          \
            const int c  = ks * 4 + quad;                                      \
            dst[nj][ks] = *(const v8s*)((hp) + rh * BK + ((c ^ xr) << 3));     \
        } } while (0)

#define MM(accq, aT, bT) do {                                                  \
        _Pragma("unroll")                                                      \
        for (int ks = 0; ks < 2; ++ks)                                         \
        _Pragma("unroll")                                                      \
        for (int mi = 0; mi < 2; ++mi)                                         \
        _Pragma("unroll")                                                      \
        for (int nj = 0; nj < 4; ++nj)                                         \
            accq[mi][nj] = __builtin_amdgcn_mfma_f32_16x16x32_bf16(            \
                aT[mi][ks], bT[nj][ks], accq[mi][nj], 0, 0, 0);                \
    } while (0)

#define BAR()   __builtin_amdgcn_s_barrier()
#define VM6()   asm volatile("s_waitcnt vmcnt(6)" ::: "memory")
#define SCHED() __builtin_amdgcn_sched_barrier(0)
#define PRIO(p) __builtin_amdgcn_s_setprio(p)

    // ---- prologue: stage tile0 (4 halves) + tile1 (3 halves); VM6 retires tile0;
    //      preload tile0's A0/B0 fragments into registers ----
    STAGE(gA, 0,   0, &As[0][0][0]);
    STAGE(gA, 128, 0, &As[0][1][0]);
    STAGE(gB, 0,   0, &Bs[0][0][0]);
    STAGE(gB, 128, 0, &Bs[0][1][0]);
    SCHED();                       // keep tile-0 loads as the oldest 8 in the vmcnt FIFO
    STAGE(gA, 0,   1, &As[1][0][0]);
    STAGE(gA, 128, 1, &As[1][1][0]);
    STAGE(gB, 0,   1, &Bs[1][0][0]);
    VM6();
    BAR();
    LDA(a0F, &As[0][0][0]);
    LDB(bF0, &Bs[0][0][0]);

#define TILE(t, b) do {                                                        \
        const int s1 = ((t) + 1) & (NT - 1);                                   \
        const int s2 = ((t) + 2) & (NT - 1);                                   \
        /* P0: MM(0,0) on preloaded {a0F,bF0}; read A1 for P1 */               \
        LDA(a1F, &As[b][1][0]);                                                \
        BAR();                                                                 \
        STAGE(gB, 128, s1, &Bs[(b) ^ 1][1][0]);                                \
        PRIO(1); MM(acc00, a0F, bF0); PRIO(0);                                 \
        /* P1: MM(1,0) on {a1F,bF0}; read B1 for P2 */                         \
        LDB(bF1, &Bs[b][1][0]);                                                \
        BAR();                                                                 \
        STAGE(gA, 0, s2, &As[b][0][0]);                                        \
        PRIO(1); MM(acc10, a1F, bF0); PRIO(0);                                 \
        /* P2: MM(0,1) on {a0F,bF1}; no reads */                               \
        BAR();                                                                 \
        STAGE(gA, 128, s2, &As[b][1][0]);                                      \
        PRIO(1); MM(acc01, a0F, bF1); PRIO(0);                                 \
        /* P3: MM(1,1) on {a1F,bF1}; counted vmcnt; prefetch next tile's A0/B0 */ \
        STAGE(gB, 0, s2, &Bs[b][0][0]);                                        \
        VM6();                                                                 \
        BAR();                                                                 \
        LDA(a0F, &As[(b) ^ 1][0][0]);                                          \
        LDB(bF0, &Bs[(b) ^ 1][0][0]);                                          \
        PRIO(1); MM(acc11, a1F, bF1); PRIO(0);                                 \
    } while (0)

    for (int t = 0; t < NT; t += 2) {
        TILE(t, 0);
        TILE(t + 1, 1);
    }

    // epilogue: C/D layout col = lane&15, row = quad*4 + reg  [m89/m91 verified]
#define WR(accq, QM, QN) do {                                                  \
        _Pragma("unroll")                                                      \
        for (int nj = 0; nj < 4; ++nj) {                                       \
            const int col = n0 + (QN) * 128 + wn2 * 64 + nj * 16 + lrow;       \
            const float bj = bias[col];                                        \
            _Pragma("unroll")                                                  \
            for (int mi = 0; mi < 2; ++mi) {                                   \
                const int row = m0 + (QM) * 128 + wm2 * 32 + mi * 16 + quad * 4; \
                float* cp = C + (size_t)row * GEMM_N + col;                    \
                _Pragma("unroll")                                              \
                for (int r = 0; r < 4; ++r)                                    \
                    cp[(size_t)r * GEMM_N] = accq[mi][nj][r] + bj;             \
            }                                                                  \
        } } while (0)

    WR(acc00, 0, 0);
    WR(acc10, 1, 0);
    WR(acc01, 0, 1);
    WR(acc11, 1, 1);

#undef STAGE
#undef LDA
#undef LDB
#undef MM
#undef BAR
#undef VM6
#undef SCHED
#undef PRIO
#undef TILE
#undef WR
}

// ---------------- launch ----------------

extern "C" void kernel_launch(void* const* d_in, const int* in_sizes, int n_in,
                              void* d_out, int out_size, void* d_ws, size_t ws_size,
                              hipStream_t stream) {
    const float* x      = (const float*)d_in[0];   // [4,2048,4096] = [8192,4096]
    const float* weight = (const float*)d_in[1];   // [4096,4096]
    const float* bias   = (const float*)d_in[2];   // [4096]
    const float* sw     = (const float*)d_in[3];   // [nnz]
    const int*   sidx   = (const int*)d_in[4];     // [2,nnz]
    const int nnz = in_sizes[3];

    const size_t welems = (size_t)GEMM_N * GEMM_K;        // 16,777,216
    const size_t xelems = (size_t)GEMM_M * GEMM_K;        // 33,554,432

    uint16_t* Wb = (uint16_t*)d_ws;
    uint16_t* Xb = (uint16_t*)((char*)d_ws + welems * sizeof(uint16_t));

    const size_t x8 = xelems / 8;
    const size_t w8 = welems / 8;
    const int prep_blocks = (int)((x8 + w8) / 256);

    prep_cvt_kernel<<<dim3(prep_blocks), 256, 0, stream>>>(x, weight, Xb, Wb, x8);
    scatter_bf16_kernel<<<dim3((nnz + 255) / 256), 256, 0, stream>>>(
        Wb, sw, sidx, sidx + nnz, nnz);
    gemm_bt_kernel<<<dim3((GEMM_M / BM) * (GEMM_N / BN)), 512, 0, stream>>>(
        Xb, Wb, bias, (float*)d_out);
}